// Round 2
// baseline (1929.484 us; speedup 1.0000x reference)
//
#include <hip/hip_runtime.h>
#include <hip/hip_bf16.h>
#include <cstdint>
#include <cstddef>

typedef __bf16 bf16_t;
typedef __bf16 bf16x8 __attribute__((ext_vector_type(8)));
typedef __bf16 bf16x4 __attribute__((ext_vector_type(4)));
typedef float  f32x4  __attribute__((ext_vector_type(4)));

#define B_  32
#define T_  128
#define H_  512
#define V_  32000
#define G4_ 2048   // 4*H
#define NB_ 64     // persistent recurrence blocks (must be 64: master poll = 1 wave)
#define HBUF_ (B_ * H_)   // u32 elems per h buffer (16384)

// ---------------- prep kernels ----------------

__global__ void convert_f32_bf16(const float* __restrict__ src, bf16_t* __restrict__ dst, int n4) {
  int i = blockIdx.x * blockDim.x + threadIdx.x;
  int stride = gridDim.x * blockDim.x;
  for (; i < n4; i += stride) {
    float4 v = ((const float4*)src)[i];
    bf16x4 o = { (bf16_t)v.x, (bf16_t)v.y, (bf16_t)v.z, (bf16_t)v.w };
    ((bf16x4*)dst)[i] = o;
  }
}

// One block per (b,t) row: tok = t==0 ? START_IDX(1) : target[b,t-1]; Xemb[row] = bf16(E[tok])
__global__ void gather_embed(const float* __restrict__ E, const int* __restrict__ target,
                             bf16_t* __restrict__ Xemb) {
  int n = blockIdx.x;               // 0..4095, row = b*T + t
  int b = n >> 7, t = n & 127;
  int tok = (t == 0) ? 1 : target[b * T_ + t - 1];
  const float4* src = (const float4*)(E + (size_t)tok * H_);
  bf16x4* dst = (bf16x4*)(Xemb + (size_t)n * H_);
  int k = threadIdx.x;              // 128 threads * 4 floats = 512
  float4 v = src[k];
  bf16x4 o = { (bf16_t)v.x, (bf16_t)v.y, (bf16_t)v.z, (bf16_t)v.w };
  dst[k] = o;
}

// bsum = b_ih + b_hh; zero the grid-barrier slots/go (re-zeroed every launch/replay)
__global__ void init_misc(const float* __restrict__ b_ih, const float* __restrict__ b_hh,
                          float* __restrict__ bsum, unsigned* __restrict__ slots,
                          unsigned* __restrict__ go) {
  int i = blockIdx.x * blockDim.x + threadIdx.x;   // 8*256 = 2048
  if (i < G4_) bsum[i] = b_ih[i] + b_hh[i];
  if (i < NB_) slots[i] = 0;
  if (i == 0) *go = 0;
}

// ---------------- bf16 MFMA GEMM: C[M,N] = A[M,512] * B[N,512]^T + bias[N] ----------------
// m97 structure: 128x128 tile, BK=64, 256 threads (4 waves, 2x2 of 64x64),
// global_load_lds width-16 staging, mfma_f32_16x16x32_bf16. (harness-verified)
__global__ __launch_bounds__(256)
void gemm_bt(const bf16_t* __restrict__ A, const bf16_t* __restrict__ Bm,
             const float* __restrict__ bias, float* __restrict__ C, int N) {
  __shared__ bf16_t As[128 * 64];
  __shared__ bf16_t Bs[128 * 64];
  const int tid  = threadIdx.x;
  const int tn   = blockIdx.x;      // N / 128
  const int tm   = blockIdx.y;      // M / 128
  const int lane = tid & 63, wid = tid >> 6;
  const int wm = (wid >> 1) * 64, wn = (wid & 1) * 64;
  const size_t K = 512;

  f32x4 acc[4][4] = {};

  for (int k0 = 0; k0 < 512; k0 += 64) {
    #pragma unroll
    for (int r = 0; r < 4; ++r) {
      int c   = r * 256 + tid;
      int row = c >> 3, kc = c & 7;
      const bf16_t* ga = A  + ((size_t)(tm * 128 + row)) * K + (size_t)k0 + kc * 8;
      const bf16_t* gb = Bm + ((size_t)(tn * 128 + row)) * K + (size_t)k0 + kc * 8;
      __builtin_amdgcn_global_load_lds((__attribute__((address_space(1))) void*)ga,
                                       (__attribute__((address_space(3))) void*)(As + c * 8),
                                       16, 0, 0);
      __builtin_amdgcn_global_load_lds((__attribute__((address_space(1))) void*)gb,
                                       (__attribute__((address_space(3))) void*)(Bs + c * 8),
                                       16, 0, 0);
    }
    __syncthreads();

    #pragma unroll
    for (int k32 = 0; k32 < 64; k32 += 32) {
      bf16x8 af[4], bfr[4];
      const int kk = k32 + (lane >> 4) * 8;
      #pragma unroll
      for (int i = 0; i < 4; ++i) {
        int ra = wm + i * 16 + (lane & 15);
        af[i]  = *(const bf16x8*)(As + ra * 64 + kk);
        int rb = wn + i * 16 + (lane & 15);
        bfr[i] = *(const bf16x8*)(Bs + rb * 64 + kk);
      }
      #pragma unroll
      for (int i = 0; i < 4; ++i)
        #pragma unroll
        for (int j = 0; j < 4; ++j)
          acc[i][j] = __builtin_amdgcn_mfma_f32_16x16x32_bf16(af[i], bfr[j], acc[i][j], 0, 0, 0);
    }
    __syncthreads();
  }

  const int m0 = tm * 128 + wm + (lane >> 4) * 4;
  const int n0 = tn * 128 + wn + (lane & 15);
  #pragma unroll
  for (int i = 0; i < 4; ++i) {
    #pragma unroll
    for (int j = 0; j < 4; ++j) {
      int nn = n0 + j * 16;
      float bv = bias ? bias[nn] : 0.f;
      #pragma unroll
      for (int r = 0; r < 4; ++r) {
        int mm = m0 + i * 16 + r;
        C[(size_t)mm * N + nn] = acc[i][j][r] + bv;
      }
    }
  }
}

// ---------------- persistent LSTM recurrence ----------------
// 64 blocks x 256 threads (4 waves). Block owns 8 h-columns (m0..m0+7) -> 32 W_hh rows
// (row order r = ml*4 + g so the 4 gates of one (b,m) are adjacent in LDS).
// W_hh resident in registers as bf16 hi/lo (bf16x3 product: hi*hi + hi*lo + lo*hi, f32 acc).
// h exchanged via packed uint32 (bf16 hi | lo<<16) DOUBLE-BUFFERED global buffer with
// agent-scope atomics (IF-coherent). Double buffer kills the step-t-store vs
// step-t-load WAR race (round-1 failure): step t reads buf[t&1], writes buf[(t+1)&1];
// the single per-step barrier covers both RAW (next step's reads) and WAR (a block
// passes the barrier only after its reads drained: __syncthreads waits vmcnt(0)).
// Grid barrier: slot-per-block release stores + block0 wave-vote master + go broadcast.

static __device__ __forceinline__ unsigned bperm_lo16(unsigned u0, unsigned u1) {
  // [u0.lo16 | u1.lo16<<16]
  return __builtin_amdgcn_perm(u1, u0, 0x05040100u);
}
static __device__ __forceinline__ unsigned bperm_hi16(unsigned u0, unsigned u1) {
  // [u0.hi16 | u1.hi16<<16]
  return __builtin_amdgcn_perm(u1, u0, 0x07060302u);
}
static __device__ __forceinline__ unsigned pack_hl(float h, bf16_t& hh_out) {
  bf16_t hh = (bf16_t)h;
  bf16_t hl = (bf16_t)(h - (float)hh);
  hh_out = hh;
  union { bf16_t b; unsigned short u; } a, b2;
  a.b = hh; b2.b = hl;
  return (unsigned)a.u | ((unsigned)b2.u << 16);
}

__device__ __forceinline__ void grid_bar(unsigned* slots, unsigned* go, unsigned tok) {
  __syncthreads();  // drains each wave's vmcnt -> this block's h_pk loads AND stores complete
  if (threadIdx.x == 0)
    __hip_atomic_store(&slots[blockIdx.x], tok, __ATOMIC_RELEASE, __HIP_MEMORY_SCOPE_AGENT);
  if (blockIdx.x == 0) {
    if (threadIdx.x < 64) {         // wave 0 = master: lane l polls slots[l] (NB_ == 64)
      for (;;) {
        unsigned v = __hip_atomic_load(&slots[threadIdx.x], __ATOMIC_ACQUIRE,
                                       __HIP_MEMORY_SCOPE_AGENT);
        if (__all((int)(v >= tok))) break;
        __builtin_amdgcn_s_sleep(1);
      }
      if (threadIdx.x == 0)
        __hip_atomic_store(go, tok, __ATOMIC_RELEASE, __HIP_MEMORY_SCOPE_AGENT);
    }
  } else if (threadIdx.x == 0) {
    while (__hip_atomic_load(go, __ATOMIC_ACQUIRE, __HIP_MEMORY_SCOPE_AGENT) < tok)
      __builtin_amdgcn_s_sleep(1);
  }
  __syncthreads();
}

__global__ __launch_bounds__(256, 1)
void lstm_persist(const float* __restrict__ Xg, const float* __restrict__ Whh,
                  const float* __restrict__ enc, unsigned* __restrict__ h_pk,
                  bf16_t* __restrict__ Hall,
                  unsigned* __restrict__ slots, unsigned* __restrict__ go) {
  __shared__ __attribute__((aligned(16))) float gsh[2][32][36];  // [khalf][batch][row r=ml*4+g], padded

  const int tid  = threadIdx.x;
  const int lane = tid & 63;
  const int w    = tid >> 6;        // wave 0..3
  const int mt   = w & 1;           // batch tile (rows mt*16..mt*16+15)
  const int kh   = w >> 1;          // K half (kh*256 .. +256)
  const int m0   = blockIdx.x * 8;  // owned h-columns
  const int rl   = lane & 15;
  const int kc   = (lane >> 4) * 8; // 8-elem k-chunk within a k32 step

  // --- W_hh fragments -> registers, bf16 hi/lo split (constant across all 128 steps) ---
  bf16x8 whi[2][8], wlo[2][8];
  #pragma unroll
  for (int nt = 0; nt < 2; ++nt) {
    const int r  = nt * 16 + rl;    // 0..31 ; r = ml*4 + g
    const int g  = r & 3, ml = r >> 2;
    const float* wrow = Whh + (size_t)(g * H_ + m0 + ml) * H_ + kh * 256 + kc;
    #pragma unroll
    for (int i = 0; i < 8; ++i) {
      float4 f0 = *(const float4*)(wrow + i * 32);
      float4 f1 = *(const float4*)(wrow + i * 32 + 4);
      bf16x8 hi8, lo8;
      hi8[0] = (bf16_t)f0.x; lo8[0] = (bf16_t)(f0.x - (float)hi8[0]);
      hi8[1] = (bf16_t)f0.y; lo8[1] = (bf16_t)(f0.y - (float)hi8[1]);
      hi8[2] = (bf16_t)f0.z; lo8[2] = (bf16_t)(f0.z - (float)hi8[2]);
      hi8[3] = (bf16_t)f0.w; lo8[3] = (bf16_t)(f0.w - (float)hi8[3]);
      hi8[4] = (bf16_t)f1.x; lo8[4] = (bf16_t)(f1.x - (float)hi8[4]);
      hi8[5] = (bf16_t)f1.y; lo8[5] = (bf16_t)(f1.y - (float)hi8[5]);
      hi8[6] = (bf16_t)f1.z; lo8[6] = (bf16_t)(f1.z - (float)hi8[6]);
      hi8[7] = (bf16_t)f1.w; lo8[7] = (bf16_t)(f1.w - (float)hi8[7]);
      whi[nt][i] = hi8; wlo[nt][i] = lo8;
    }
  }

  // --- state: thread (pb, pml) owns c[pb][m0+pml] in a register for all steps ---
  const int pb  = tid >> 3;         // 0..31
  const int pml = tid & 7;          // 0..7
  const int pm  = m0 + pml;
  float c = enc[pb * H_ + pm];      // h0 = c0 = encoder state
  {
    bf16_t dummy;
    unsigned pkv = pack_hl(c, dummy);
    // h0 -> buffer 0 (step 0 reads buf[0])
    __hip_atomic_store(&h_pk[pb * H_ + pm], pkv, __ATOMIC_RELAXED, __HIP_MEMORY_SCOPE_AGENT);
  }
  grid_bar(slots, go, 1u);

  const unsigned abase = (unsigned)(mt * 16 + rl) * H_ + (unsigned)(kh * 256 + kc);

  for (int t = 0; t < T_; ++t) {
    const unsigned rboff = (unsigned)(t & 1) * HBUF_;        // read buffer
    const unsigned wboff = (unsigned)((t + 1) & 1) * HBUF_;  // write buffer

    // Xg prefetch (independent of h; hides under the gate GEMM)
    const float* xg = Xg + ((size_t)pb * T_ + t) * G4_ + pm;
    float x0 = xg[0], x1 = xg[512], x2 = xg[1024], x3 = xg[1536];

    // h fragment loads: 32 x 8B agent-scope loads (IF-coherent), all in flight at once
    unsigned long long pkv[8][4];
    #pragma unroll
    for (int i = 0; i < 8; ++i) {
      const unsigned long long* hp =
          (const unsigned long long*)(h_pk + rboff + abase + i * 32);
      #pragma unroll
      for (int q = 0; q < 4; ++q)
        pkv[i][q] = __hip_atomic_load(hp + q, __ATOMIC_RELAXED, __HIP_MEMORY_SCOPE_AGENT);
    }

    // gates[mt-tile][r] partial (this wave's K half), bf16x3: 3 independent acc chains per nt
    f32x4 acc[2][3] = {};
    #pragma unroll
    for (int i = 0; i < 8; ++i) {
      unsigned u0 = (unsigned)pkv[i][0], u1 = (unsigned)(pkv[i][0] >> 32);
      unsigned u2 = (unsigned)pkv[i][1], u3 = (unsigned)(pkv[i][1] >> 32);
      unsigned u4 = (unsigned)pkv[i][2], u5 = (unsigned)(pkv[i][2] >> 32);
      unsigned u6 = (unsigned)pkv[i][3], u7 = (unsigned)(pkv[i][3] >> 32);
      union { unsigned u[4]; bf16x8 v; } ah, al;
      ah.u[0] = bperm_lo16(u0, u1); ah.u[1] = bperm_lo16(u2, u3);
      ah.u[2] = bperm_lo16(u4, u5); ah.u[3] = bperm_lo16(u6, u7);
      al.u[0] = bperm_hi16(u0, u1); al.u[1] = bperm_hi16(u2, u3);
      al.u[2] = bperm_hi16(u4, u5); al.u[3] = bperm_hi16(u6, u7);
      acc[0][0] = __builtin_amdgcn_mfma_f32_16x16x32_bf16(ah.v, whi[0][i], acc[0][0], 0, 0, 0);
      acc[1][0] = __builtin_amdgcn_mfma_f32_16x16x32_bf16(ah.v, whi[1][i], acc[1][0], 0, 0, 0);
      acc[0][1] = __builtin_amdgcn_mfma_f32_16x16x32_bf16(ah.v, wlo[0][i], acc[0][1], 0, 0, 0);
      acc[1][1] = __builtin_amdgcn_mfma_f32_16x16x32_bf16(ah.v, wlo[1][i], acc[1][1], 0, 0, 0);
      acc[0][2] = __builtin_amdgcn_mfma_f32_16x16x32_bf16(al.v, whi[0][i], acc[0][2], 0, 0, 0);
      acc[1][2] = __builtin_amdgcn_mfma_f32_16x16x32_bf16(al.v, whi[1][i], acc[1][2], 0, 0, 0);
    }

    // write partial gate tiles (C layout: col = lane&15 = r, row = (lane>>4)*4+reg = batch)
    #pragma unroll
    for (int nt = 0; nt < 2; ++nt) {
      f32x4 s = acc[nt][0] + acc[nt][1] + acc[nt][2];
      #pragma unroll
      for (int q = 0; q < 4; ++q)
        gsh[kh][mt * 16 + (lane >> 4) * 4 + q][nt * 16 + rl] = s[q];
    }
    __syncthreads();

    // pointwise: thread (pb, pml); gates adjacent since r = ml*4 + g
    float4 v0 = *(const float4*)&gsh[0][pb][pml * 4];
    float4 v1 = *(const float4*)&gsh[1][pb][pml * 4];
    float gi = v0.x + v1.x + x0;
    float gf = v0.y + v1.y + x1;
    float gg = v0.z + v1.z + x2;
    float gv = v0.w + v1.w + x3;
    float si = 1.f / (1.f + expf(-gi));
    float sf = 1.f / (1.f + expf(-gf));
    float tg = tanhf(gg);
    float so = 1.f / (1.f + expf(-gv));
    c = sf * c + si * tg;
    float h = so * tanhf(c);
    bf16_t hh;
    unsigned pko = pack_hl(h, hh);
    Hall[((size_t)pb * T_ + t) * H_ + pm] = hh;
    __hip_atomic_store(&h_pk[wboff + pb * H_ + pm], pko, __ATOMIC_RELAXED,
                       __HIP_MEMORY_SCOPE_AGENT);

    if (t < T_ - 1) grid_bar(slots, go, (unsigned)(t + 2));
  }
}

// ---------------- launch ----------------

extern "C" void kernel_launch(void* const* d_in, const int* in_sizes, int n_in,
                              void* d_out, int out_size, void* d_ws, size_t ws_size,
                              hipStream_t stream) {
  const float* enc    = (const float*)d_in[0];
  const int*   target = (const int*)  d_in[1];
  const float* E      = (const float*)d_in[2];
  const float* W_ih   = (const float*)d_in[3];
  const float* W_hh   = (const float*)d_in[4];
  const float* b_ih   = (const float*)d_in[5];
  const float* b_hh   = (const float*)d_in[6];
  const float* b_out  = (const float*)d_in[7];
  float* out = (float*)d_out;

  char* p = (char*)d_ws;
  bf16_t*  E_bf   = (bf16_t*)p;   p += (size_t)V_ * H_ * 2;        // 32.77 MB
  bf16_t*  Wih_bf = (bf16_t*)p;   p += (size_t)G4_ * H_ * 2;       //  2.10 MB
  bf16_t*  Xemb   = (bf16_t*)p;   p += (size_t)B_ * T_ * H_ * 2;   //  4.19 MB
  bf16_t*  Hall   = (bf16_t*)p;   p += (size_t)B_ * T_ * H_ * 2;   //  4.19 MB
  float*   Xg     = (float*)p;    p += (size_t)B_ * T_ * G4_ * 4;  // 33.55 MB
  float*   bsum   = (float*)p;    p += (size_t)G4_ * 4;
  unsigned* h_pk  = (unsigned*)p; p += (size_t)2 * HBUF_ * 4;      // 128 KB (double-buffered)
  unsigned* slots = (unsigned*)p; p += NB_ * 4;
  unsigned* go    = (unsigned*)p; p += 256;

  // prep: casts, embedding gather, bias sum + barrier reset
  convert_f32_bf16<<<2048, 256, 0, stream>>>(E, E_bf, V_ * H_ / 4);
  convert_f32_bf16<<<256, 256, 0, stream>>>(W_ih, Wih_bf, G4_ * H_ / 4);
  gather_embed<<<B_ * T_, 128, 0, stream>>>(E, target, Xemb);
  init_misc<<<8, 256, 0, stream>>>(b_ih, b_hh, bsum, slots, go);

  // Xg[4096, 2048] = Xemb @ W_ih^T + (b_ih + b_hh)
  dim3 g1(G4_ / 128, (B_ * T_) / 128);
  gemm_bt<<<g1, 256, 0, stream>>>(Xemb, Wih_bf, bsum, Xg, G4_);

  // entire 128-step recurrence in one persistent kernel
  lstm_persist<<<NB_, 256, 0, stream>>>(Xg, W_hh, enc, h_pk, Hall, slots, go);

  // logits[4096, 32000] = Hall @ E^T + b_out
  dim3 g2(V_ / 128, (B_ * T_) / 128);
  gemm_bt<<<g2, 256, 0, stream>>>(Hall, E_bf, b_out, out, V_);
}